// Round 13
// baseline (236.279 us; speedup 1.0000x reference)
//
#include <hip/hip_runtime.h>

#define N_NODES 50000
#define N_EDGES 800000
#define N_GRAPHS 256
#define F 64
#define NBUCK 196          // ceil(50000/256) coarse buckets (dst>>8)
#define CAP 4608           // per-bucket capacity (mean 4082, sd ~64 -> 8 sigma)
#define P3_TILE 2048
#define P3_GRID ((N_EDGES + P3_TILE - 1) / P3_TILE)
#define BCAP 6144
#define DBINS 64           // degree bins for balance sort (degree capped at 63)

// ---- bf16 helpers (RTN), all math stays f32 ----
__device__ __forceinline__ unsigned short f2bf(float f) {
    union { float f; unsigned u; } c; c.f = f;
    unsigned u = c.u + 0x7FFFu + ((c.u >> 16) & 1u);
    return (unsigned short)(u >> 16);
}
__device__ __forceinline__ unsigned pack2bf(float lo, float hi) {
    return (unsigned)f2bf(lo) | ((unsigned)f2bf(hi) << 16);
}
__device__ __forceinline__ float bfl(unsigned u) {
    union { unsigned u; float f; } c; c.u = u << 16; return c.f;
}
__device__ __forceinline__ float bfh(unsigned u) {
    union { unsigned u; float f; } c; c.u = u & 0xFFFF0000u; return c.f;
}

// ---------------- P1: partition edges into fixed-capacity buckets ----------------
__global__ __launch_bounds__(256) void partition_edges(const int* __restrict__ src,
                                                       const int* __restrict__ dst,
                                                       int* __restrict__ bcur,
                                                       unsigned int* __restrict__ bpair) {
    __shared__ int bh[NBUCK], bloc[NBUCK], bpos[NBUCK];
    int t = threadIdx.x;
    int lo = blockIdx.x * P3_TILE;
    int hi = min(lo + P3_TILE, N_EDGES);
    for (int i = t; i < NBUCK; i += 256) { bh[i] = 0; bpos[i] = 0; }
    __syncthreads();
    for (int e = lo + t; e < hi; e += 256) atomicAdd(&bh[dst[e] >> 8], 1);
    __syncthreads();
    for (int i = t; i < NBUCK; i += 256)
        bloc[i] = bh[i] ? atomicAdd(&bcur[i], bh[i]) : 0;
    __syncthreads();
    for (int e = lo + t; e < hi; e += 256) {
        int d = dst[e];
        int b = d >> 8;
        int r = atomicAdd(&bpos[b], 1);
        bpair[(size_t)b * CAP + bloc[b] + r] = ((unsigned)src[e] << 8) | (unsigned)(d & 255);
    }
}

// ---------------- P2: per-bucket counting sort -> eidx, rbeg/rend, dinv, degree hist ----------------
__global__ __launch_bounds__(256) void bucket_sort(const unsigned int* __restrict__ bpair,
                                                   const int* __restrict__ bcur,
                                                   int* __restrict__ eidx,
                                                   int* __restrict__ rbeg,
                                                   int* __restrict__ rend,
                                                   float* __restrict__ dinv,
                                                   int* __restrict__ dhist) {
    __shared__ int cnt[256], s[256], pos[256];
    __shared__ int lout[BCAP];
    __shared__ int ldh[DBINS];
    int b = blockIdx.x, t = threadIdx.x;
    int base = b * CAP;
    int sz = bcur[b];

    cnt[t] = 0;
    if (t < DBINS) ldh[t] = 0;
    __syncthreads();
    for (int i = t; i < sz; i += 256) atomicAdd(&cnt[bpair[base + i] & 255], 1);
    __syncthreads();
    int v = cnt[t];
    s[t] = v;
    __syncthreads();
    for (int off = 1; off < 256; off <<= 1) {
        int u = (t >= off) ? s[t - off] : 0;
        __syncthreads();
        s[t] += u;
        __syncthreads();
    }
    int excl = s[t] - v;
    pos[t] = excl;
    int node = b * 256 + t;
    if (node < N_NODES) {
        rbeg[node] = base + excl;
        rend[node] = base + excl + v;
        dinv[node] = 1.0f / sqrtf((float)v + 1.0f);   // +1 self-loop
        atomicAdd(&ldh[min(v, DBINS - 1)], 1);        // degree histogram
    }
    __syncthreads();
    if (t < DBINS && ldh[t]) atomicAdd(&dhist[t], ldh[t]);

    if (sz <= BCAP) {
        for (int i = t; i < sz; i += 256) {
            unsigned p = bpair[base + i];
            int r = atomicAdd(&pos[p & 255], 1);
            lout[r] = (int)((p >> 8) << 7);   // src byte offset (src*128, bf16 row)
        }
        __syncthreads();
        for (int i = t; i < sz; i += 256) eidx[base + i] = lout[i];
    } else {
        for (int i = t; i < sz; i += 256) {
            unsigned p = bpair[base + i];
            int r = atomicAdd(&pos[p & 255], 1);
            eidx[base + r] = (int)((p >> 8) << 7);
        }
    }
}

// ---------------- P3: scan degree bins -> cursors ----------------
__global__ __launch_bounds__(64) void dscan(const int* __restrict__ dhist,
                                            int* __restrict__ dcur) {
    __shared__ int s[DBINS];
    int t = threadIdx.x;
    int v = dhist[t];
    s[t] = v;
    __syncthreads();
    for (int off = 1; off < DBINS; off <<= 1) {
        int u = (t >= off) ? s[t - off] : 0;
        __syncthreads();
        s[t] += u;
        __syncthreads();
    }
    dcur[t] = s[t] - v;   // exclusive
}

// ---------------- P4: scatter nodes into degree-sorted permutation ----------------
__global__ __launch_bounds__(256) void dscatter(const int* __restrict__ rbeg,
                                                const int* __restrict__ rend,
                                                int* __restrict__ dcur,
                                                int* __restrict__ perm) {
    __shared__ int lh[DBINS], lbase[DBINS], lpos[DBINS];
    int t = threadIdx.x;
    int node = blockIdx.x * 256 + t;
    for (int i = t; i < DBINS; i += 256) { lh[i] = 0; lpos[i] = 0; }
    __syncthreads();
    int bin = 0;
    bool valid = node < N_NODES;
    if (valid) {
        bin = min(rend[node] - rbeg[node], DBINS - 1);
        atomicAdd(&lh[bin], 1);
    }
    __syncthreads();
    if (t < DBINS) lbase[t] = lh[t] ? atomicAdd(&dcur[t], lh[t]) : 0;
    __syncthreads();
    if (valid) {
        int r = atomicAdd(&lpos[bin], 1);
        perm[lbase[bin] + r] = node;
    }
}

// ---------------- GEMM + dinv fold: Hn[i,:] = bf16( (X[i,:] @ W) * dinv[i] ) ----------------
#define XSTRIDE 17
template <bool BF16IN>
__global__ __launch_bounds__(256) void gemm64_t(const void* __restrict__ Xv,
                                                const float* __restrict__ W,
                                                const float* __restrict__ dinv,
                                                unsigned short* __restrict__ Hn, int n) {
    __shared__ float4 sW[64 * 16];
    __shared__ float4 sX[128 * XSTRIDE];
    int tid = threadIdx.x;
    int base = blockIdx.x * 128;

    const float4* W4 = (const float4*)W;
    for (int i = tid; i < 64 * 16; i += 256) sW[i] = W4[i];
    if (BF16IN) {
        const uint4* X4 = (const uint4*)Xv;    // row = 8 uint4 (64 bf16)
        for (int i = tid; i < 128 * 8; i += 256) {
            int r = i >> 3, c = i & 7;
            int node = base + r;
            uint4 u = (node < n) ? X4[(size_t)node * 8 + c]
                                 : make_uint4(0u, 0u, 0u, 0u);
            sX[r * XSTRIDE + 2 * c]     = make_float4(bfl(u.x), bfh(u.x), bfl(u.y), bfh(u.y));
            sX[r * XSTRIDE + 2 * c + 1] = make_float4(bfl(u.z), bfh(u.z), bfl(u.w), bfh(u.w));
        }
    } else {
        const float4* X4 = (const float4*)Xv;
        for (int i = tid; i < 128 * 16; i += 256) {
            int r = i >> 4, kg = i & 15;
            int node = base + r;
            sX[r * XSTRIDE + kg] = (node < n) ? X4[(size_t)node * 16 + kg]
                                              : make_float4(0.f, 0.f, 0.f, 0.f);
        }
    }
    __syncthreads();

    int fg = tid & 15;
    int ng = tid >> 4;
    float4 acc[8];
#pragma unroll
    for (int ii = 0; ii < 8; ii++) acc[ii] = make_float4(0.f, 0.f, 0.f, 0.f);

    for (int kg = 0; kg < 16; kg++) {
        float4 xv[8];
#pragma unroll
        for (int ii = 0; ii < 8; ii++) xv[ii] = sX[(ng + 16 * ii) * XSTRIDE + kg];
#pragma unroll
        for (int kk = 0; kk < 4; kk++) {
            float4 wv = sW[(4 * kg + kk) * 16 + fg];
#pragma unroll
            for (int ii = 0; ii < 8; ii++) {
                float xs = (kk == 0) ? xv[ii].x : (kk == 1) ? xv[ii].y
                         : (kk == 2) ? xv[ii].z : xv[ii].w;
                acc[ii].x += wv.x * xs;
                acc[ii].y += wv.y * xs;
                acc[ii].z += wv.z * xs;
                acc[ii].w += wv.w * xs;
            }
        }
    }

    ushort4* H4 = (ushort4*)Hn;
#pragma unroll
    for (int ii = 0; ii < 8; ii++) {
        int node = base + ng + 16 * ii;
        if (node < n) {
            float d = dinv[node];
            float4 o = acc[ii];
            ushort4 u;
            u.x = f2bf(o.x * d); u.y = f2bf(o.y * d);
            u.z = f2bf(o.z * d); u.w = f2bf(o.w * d);
            H4[(size_t)node * 16 + fg] = u;
        }
    }
}

// ---------------- gather (layers 1,2): 8 degree-matched nodes/wave via perm ----------------
__global__ __launch_bounds__(256) void gather_layer(const int* __restrict__ perm,
                                                    const int* __restrict__ rbeg,
                                                    const int* __restrict__ rend,
                                                    const int* __restrict__ eidx,
                                                    const float* __restrict__ dinv,
                                                    const unsigned short* __restrict__ Hn,
                                                    const float* __restrict__ b,
                                                    unsigned short* __restrict__ OUT, int n) {
    int wv = (blockIdx.x * blockDim.x + threadIdx.x) >> 6;
    int lane = threadIdx.x & 63;
    int ns = lane >> 3, f = lane & 7;
    int slot = wv * 8 + ns;
    bool valid = slot < n;
    int node = valid ? perm[slot] : 0;
    int beg = valid ? rbeg[node] : 0;
    int end = valid ? rend[node] : 0;
    const char* Hb = (const char*)Hn;

    float a0 = 0.f, a1 = 0.f, a2 = 0.f, a3 = 0.f;
    float a4 = 0.f, a5 = 0.f, a6 = 0.f, a7 = 0.f;
    int k = beg;
    for (; k + 1 < end; k += 2) {
        int o1 = eidx[k];
        int o2 = eidx[k + 1];
        uint4 p = *(const uint4*)(Hb + o1 + f * 16);
        uint4 q = *(const uint4*)(Hb + o2 + f * 16);
        a0 += bfl(p.x) + bfl(q.x); a1 += bfh(p.x) + bfh(q.x);
        a2 += bfl(p.y) + bfl(q.y); a3 += bfh(p.y) + bfh(q.y);
        a4 += bfl(p.z) + bfl(q.z); a5 += bfh(p.z) + bfh(q.z);
        a6 += bfl(p.w) + bfl(q.w); a7 += bfh(p.w) + bfh(q.w);
    }
    if (k < end) {
        int o1 = eidx[k];
        uint4 p = *(const uint4*)(Hb + o1 + f * 16);
        a0 += bfl(p.x); a1 += bfh(p.x);
        a2 += bfl(p.y); a3 += bfh(p.y);
        a4 += bfl(p.z); a5 += bfh(p.z);
        a6 += bfl(p.w); a7 += bfh(p.w);
    }

    if (valid) {
        float di = dinv[node];
        uint4 hs = *(const uint4*)(Hb + (size_t)node * 128 + f * 16);
        float4 b0 = ((const float4*)b)[2 * f];
        float4 b1 = ((const float4*)b)[2 * f + 1];
        float v0 = fmaxf(di * (a0 + bfl(hs.x)) + b0.x, 0.f);
        float v1 = fmaxf(di * (a1 + bfh(hs.x)) + b0.y, 0.f);
        float v2 = fmaxf(di * (a2 + bfl(hs.y)) + b0.z, 0.f);
        float v3 = fmaxf(di * (a3 + bfh(hs.y)) + b0.w, 0.f);
        float v4 = fmaxf(di * (a4 + bfl(hs.z)) + b1.x, 0.f);
        float v5 = fmaxf(di * (a5 + bfh(hs.z)) + b1.y, 0.f);
        float v6 = fmaxf(di * (a6 + bfl(hs.w)) + b1.z, 0.f);
        float v7 = fmaxf(di * (a7 + bfh(hs.w)) + b1.w, 0.f);
        uint4 u;
        u.x = pack2bf(v0, v1); u.y = pack2bf(v2, v3);
        u.z = pack2bf(v4, v5); u.w = pack2bf(v6, v7);
        ((uint4*)OUT)[(size_t)node * 8 + f] = u;
    }
}

// ---------------- layer-3 gather fused with pooling dot ----------------
__global__ __launch_bounds__(256) void gather_pool(const int* __restrict__ perm,
                                                   const int* __restrict__ rbeg,
                                                   const int* __restrict__ rend,
                                                   const int* __restrict__ eidx,
                                                   const float* __restrict__ dinv,
                                                   const unsigned short* __restrict__ Hn,
                                                   const float* __restrict__ b,
                                                   const float* __restrict__ Wl,
                                                   float* __restrict__ pdot, int n) {
    int wv = (blockIdx.x * blockDim.x + threadIdx.x) >> 6;
    int lane = threadIdx.x & 63;
    int ns = lane >> 3, f = lane & 7;
    int slot = wv * 8 + ns;
    bool valid = slot < n;
    int node = valid ? perm[slot] : 0;
    int beg = valid ? rbeg[node] : 0;
    int end = valid ? rend[node] : 0;
    const char* Hb = (const char*)Hn;

    float a0 = 0.f, a1 = 0.f, a2 = 0.f, a3 = 0.f;
    float a4 = 0.f, a5 = 0.f, a6 = 0.f, a7 = 0.f;
    int k = beg;
    for (; k + 1 < end; k += 2) {
        int o1 = eidx[k];
        int o2 = eidx[k + 1];
        uint4 p = *(const uint4*)(Hb + o1 + f * 16);
        uint4 q = *(const uint4*)(Hb + o2 + f * 16);
        a0 += bfl(p.x) + bfl(q.x); a1 += bfh(p.x) + bfh(q.x);
        a2 += bfl(p.y) + bfl(q.y); a3 += bfh(p.y) + bfh(q.y);
        a4 += bfl(p.z) + bfl(q.z); a5 += bfh(p.z) + bfh(q.z);
        a6 += bfl(p.w) + bfl(q.w); a7 += bfh(p.w) + bfh(q.w);
    }
    if (k < end) {
        int o1 = eidx[k];
        uint4 p = *(const uint4*)(Hb + o1 + f * 16);
        a0 += bfl(p.x); a1 += bfh(p.x);
        a2 += bfl(p.y); a3 += bfh(p.y);
        a4 += bfl(p.z); a5 += bfh(p.z);
        a6 += bfl(p.w); a7 += bfh(p.w);
    }

    float di = valid ? dinv[node] : 0.f;
    uint4 hs = valid ? *(const uint4*)(Hb + (size_t)node * 128 + f * 16)
                     : make_uint4(0u, 0u, 0u, 0u);
    float4 b0 = ((const float4*)b)[2 * f];
    float4 b1 = ((const float4*)b)[2 * f + 1];
    float4 w0 = ((const float4*)Wl)[2 * f];
    float4 w1 = ((const float4*)Wl)[2 * f + 1];
    float d = 0.f;
    d += fmaxf(di * (a0 + bfl(hs.x)) + b0.x, 0.f) * w0.x;
    d += fmaxf(di * (a1 + bfh(hs.x)) + b0.y, 0.f) * w0.y;
    d += fmaxf(di * (a2 + bfl(hs.y)) + b0.z, 0.f) * w0.z;
    d += fmaxf(di * (a3 + bfh(hs.y)) + b0.w, 0.f) * w0.w;
    d += fmaxf(di * (a4 + bfl(hs.z)) + b1.x, 0.f) * w1.x;
    d += fmaxf(di * (a5 + bfh(hs.z)) + b1.y, 0.f) * w1.y;
    d += fmaxf(di * (a6 + bfl(hs.w)) + b1.z, 0.f) * w1.z;
    d += fmaxf(di * (a7 + bfh(hs.w)) + b1.w, 0.f) * w1.w;
#pragma unroll
    for (int m = 1; m <= 4; m <<= 1) d += __shfl_xor(d, m);
    if (valid && f == 0) pdot[node] = d;
}

// ---------------- final: per-graph mean of pdot + bias ----------------
__global__ __launch_bounds__(64) void final_out(const float* __restrict__ pdot,
                                                const int* __restrict__ batch,
                                                const float* __restrict__ bl,
                                                float* __restrict__ out) {
    int g = blockIdx.x;
    __shared__ int slo, shi;
    int lane = threadIdx.x;
    if (lane == 0) {
        int a = 0, b = N_NODES;
        while (a < b) { int m = (a + b) >> 1; if (batch[m] < g) a = m + 1; else b = m; }
        slo = a;
        b = N_NODES;
        while (a < b) { int m = (a + b) >> 1; if (batch[m] < g + 1) a = m + 1; else b = m; }
        shi = a;
    }
    __syncthreads();
    int lo = slo, hi = shi;
    float acc = 0.f;
    for (int i = lo + lane; i < hi; i += 64) acc += pdot[i];
#pragma unroll
    for (int off = 32; off > 0; off >>= 1) acc += __shfl_down(acc, off);
    if (lane == 0) {
        float cnt = (float)(hi - lo);
        out[g] = acc / fmaxf(cnt, 1.0f) + bl[0];
    }
}

extern "C" void kernel_launch(void* const* d_in, const int* in_sizes, int n_in,
                              void* d_out, int out_size, void* d_ws, size_t ws_size,
                              hipStream_t stream) {
    const float* x     = (const float*)d_in[0];
    const int*   src   = (const int*)d_in[1];
    const int*   dst   = (const int*)d_in[2];
    const int*   batch = (const int*)d_in[3];
    const float* W1 = (const float*)d_in[4];  const float* b1 = (const float*)d_in[5];
    const float* W2 = (const float*)d_in[6];  const float* b2 = (const float*)d_in[7];
    const float* W3 = (const float*)d_in[8];  const float* b3 = (const float*)d_in[9];
    const float* Wl = (const float*)d_in[10]; const float* bl = (const float*)d_in[11];
    float* out = (float*)d_out;

    char* ws = (char*)d_ws;
    unsigned short* Abf = (unsigned short*)ws;                       // N*F bf16 (Hn)
    unsigned short* Bbf = Abf + (size_t)N_NODES * F;                 // N*F bf16 (H)
    float* dinv    = (float*)(Bbf + (size_t)N_NODES * F);            // N
    float* pdot    = dinv + N_NODES;                                 // N
    int*   rbeg    = (int*)(pdot + N_NODES);                         // N
    int*   rend    = rbeg + N_NODES;                                 // N
    int*   perm    = rend + N_NODES;                                 // N
    int*   bcur    = perm + N_NODES;                                 // NBUCK
    int*   dhist   = bcur + NBUCK;                                   // DBINS
    int*   dcur    = dhist + DBINS;                                  // DBINS
    unsigned int* bpair = (unsigned int*)(dcur + DBINS);             // NBUCK*CAP
    int*   eidx    = (int*)(bpair + (size_t)NBUCK * CAP);            // NBUCK*CAP

    const int GEMM_GRID   = (N_NODES + 127) / 128;                   // 391
    const int GATHER_GRID = (N_NODES + 31) / 32;                     // 1563
    const int NODE_GRID   = (N_NODES + 255) / 256;                   // 196

    // ---- preprocessing: padded-CSR + degree-sorted perm ----
    hipMemsetAsync(bcur, 0, (NBUCK + DBINS) * sizeof(int), stream);  // bcur + dhist
    partition_edges<<<P3_GRID, 256, 0, stream>>>(src, dst, bcur, bpair);
    bucket_sort<<<NBUCK, 256, 0, stream>>>(bpair, bcur, eidx, rbeg, rend, dinv, dhist);
    dscan<<<1, DBINS, 0, stream>>>(dhist, dcur);
    dscatter<<<NODE_GRID, 256, 0, stream>>>(rbeg, rend, dcur, perm);

    // ---- layer 1 (f32 input) ----
    gemm64_t<false><<<GEMM_GRID, 256, 0, stream>>>((const void*)x, W1, dinv, Abf, N_NODES);
    gather_layer<<<GATHER_GRID, 256, 0, stream>>>(perm, rbeg, rend, eidx, dinv, Abf, b1, Bbf, N_NODES);

    // ---- layer 2 (bf16 input) ----
    gemm64_t<true><<<GEMM_GRID, 256, 0, stream>>>((const void*)Bbf, W2, dinv, Abf, N_NODES);
    gather_layer<<<GATHER_GRID, 256, 0, stream>>>(perm, rbeg, rend, eidx, dinv, Abf, b2, Bbf, N_NODES);

    // ---- layer 3 (bf16 input), gather fused with pooling dot ----
    gemm64_t<true><<<GEMM_GRID, 256, 0, stream>>>((const void*)Bbf, W3, dinv, Abf, N_NODES);
    gather_pool<<<GATHER_GRID, 256, 0, stream>>>(perm, rbeg, rend, eidx, dinv, Abf, b3, Wl, pdot, N_NODES);

    // ---- final: per-graph mean + bias ----
    final_out<<<N_GRAPHS, 64, 0, stream>>>(pdot, batch, bl, out);
}

// Round 14
// 210.698 us; speedup vs baseline: 1.1214x; 1.1214x over previous
//
#include <hip/hip_runtime.h>

#define N_NODES 50000
#define N_EDGES 800000
#define N_GRAPHS 256
#define F 64
#define NBUCK 196          // ceil(50000/256) coarse buckets (dst>>8)
#define CAP 4608           // per-bucket capacity (mean 4082, sd ~64 -> 8 sigma)
#define P3_TILE 2048
#define P3_GRID ((N_EDGES + P3_TILE - 1) / P3_TILE)
#define BCAP 6144

// ---- bf16 helpers (RTN), all math stays f32 ----
__device__ __forceinline__ unsigned short f2bf(float f) {
    union { float f; unsigned u; } c; c.f = f;
    unsigned u = c.u + 0x7FFFu + ((c.u >> 16) & 1u);
    return (unsigned short)(u >> 16);
}
__device__ __forceinline__ unsigned pack2bf(float lo, float hi) {
    return (unsigned)f2bf(lo) | ((unsigned)f2bf(hi) << 16);
}
__device__ __forceinline__ float bfl(unsigned u) {
    union { unsigned u; float f; } c; c.u = u << 16; return c.f;
}
__device__ __forceinline__ float bfh(unsigned u) {
    union { unsigned u; float f; } c; c.u = u & 0xFFFF0000u; return c.f;
}

// ---------------- P1: partition edges into fixed-capacity buckets ----------------
__global__ __launch_bounds__(256) void partition_edges(const int* __restrict__ src,
                                                       const int* __restrict__ dst,
                                                       int* __restrict__ bcur,
                                                       unsigned int* __restrict__ bpair) {
    __shared__ int bh[NBUCK], bloc[NBUCK], bpos[NBUCK];
    int t = threadIdx.x;
    int lo = blockIdx.x * P3_TILE;
    int hi = min(lo + P3_TILE, N_EDGES);
    for (int i = t; i < NBUCK; i += 256) { bh[i] = 0; bpos[i] = 0; }
    __syncthreads();
    for (int e = lo + t; e < hi; e += 256) atomicAdd(&bh[dst[e] >> 8], 1);
    __syncthreads();
    for (int i = t; i < NBUCK; i += 256)
        bloc[i] = bh[i] ? atomicAdd(&bcur[i], bh[i]) : 0;
    __syncthreads();
    for (int e = lo + t; e < hi; e += 256) {
        int d = dst[e];
        int b = d >> 8;
        int r = atomicAdd(&bpos[b], 1);
        bpair[(size_t)b * CAP + bloc[b] + r] = ((unsigned)src[e] << 8) | (unsigned)(d & 255);
    }
}

// ---------------- P2: per-bucket LDS counting sort -> eidx (src*128), rbeg/rend, dinv ----------------
__global__ __launch_bounds__(256) void bucket_sort(const unsigned int* __restrict__ bpair,
                                                   const int* __restrict__ bcur,
                                                   int* __restrict__ eidx,
                                                   int* __restrict__ rbeg,
                                                   int* __restrict__ rend,
                                                   float* __restrict__ dinv) {
    __shared__ int cnt[256], s[256], pos[256];
    __shared__ int lout[BCAP];
    int b = blockIdx.x, t = threadIdx.x;
    int base = b * CAP;
    int sz = bcur[b];

    cnt[t] = 0;
    __syncthreads();
    for (int i = t; i < sz; i += 256) atomicAdd(&cnt[bpair[base + i] & 255], 1);
    __syncthreads();
    int v = cnt[t];
    s[t] = v;
    __syncthreads();
    for (int off = 1; off < 256; off <<= 1) {
        int u = (t >= off) ? s[t - off] : 0;
        __syncthreads();
        s[t] += u;
        __syncthreads();
    }
    int excl = s[t] - v;
    pos[t] = excl;
    int node = b * 256 + t;
    if (node < N_NODES) {
        rbeg[node] = base + excl;
        rend[node] = base + excl + v;
        dinv[node] = 1.0f / sqrtf((float)v + 1.0f);   // +1 self-loop
    }
    __syncthreads();

    if (sz <= BCAP) {
        for (int i = t; i < sz; i += 256) {
            unsigned p = bpair[base + i];
            int r = atomicAdd(&pos[p & 255], 1);
            lout[r] = (int)((p >> 8) << 7);   // src byte offset (src*128, bf16 row)
        }
        __syncthreads();
        for (int i = t; i < sz; i += 256) eidx[base + i] = lout[i];
    } else {
        for (int i = t; i < sz; i += 256) {
            unsigned p = bpair[base + i];
            int r = atomicAdd(&pos[p & 255], 1);
            eidx[base + r] = (int)((p >> 8) << 7);
        }
    }
}

// ---------------- GEMM + dinv fold: Hn[i,:] = bf16( (X[i,:] @ W) * dinv[i] ) ----------------
#define XSTRIDE 17
template <bool BF16IN>
__global__ __launch_bounds__(256) void gemm64_t(const void* __restrict__ Xv,
                                                const float* __restrict__ W,
                                                const float* __restrict__ dinv,
                                                unsigned short* __restrict__ Hn, int n) {
    __shared__ float4 sW[64 * 16];
    __shared__ float4 sX[128 * XSTRIDE];
    int tid = threadIdx.x;
    int base = blockIdx.x * 128;

    const float4* W4 = (const float4*)W;
    for (int i = tid; i < 64 * 16; i += 256) sW[i] = W4[i];
    if (BF16IN) {
        const uint4* X4 = (const uint4*)Xv;    // row = 8 uint4 (64 bf16)
        for (int i = tid; i < 128 * 8; i += 256) {
            int r = i >> 3, c = i & 7;
            int node = base + r;
            uint4 u = (node < n) ? X4[(size_t)node * 8 + c]
                                 : make_uint4(0u, 0u, 0u, 0u);
            sX[r * XSTRIDE + 2 * c]     = make_float4(bfl(u.x), bfh(u.x), bfl(u.y), bfh(u.y));
            sX[r * XSTRIDE + 2 * c + 1] = make_float4(bfl(u.z), bfh(u.z), bfl(u.w), bfh(u.w));
        }
    } else {
        const float4* X4 = (const float4*)Xv;
        for (int i = tid; i < 128 * 16; i += 256) {
            int r = i >> 4, kg = i & 15;
            int node = base + r;
            sX[r * XSTRIDE + kg] = (node < n) ? X4[(size_t)node * 16 + kg]
                                              : make_float4(0.f, 0.f, 0.f, 0.f);
        }
    }
    __syncthreads();

    int fg = tid & 15;
    int ng = tid >> 4;
    float4 acc[8];
#pragma unroll
    for (int ii = 0; ii < 8; ii++) acc[ii] = make_float4(0.f, 0.f, 0.f, 0.f);

    for (int kg = 0; kg < 16; kg++) {
        float4 xv[8];
#pragma unroll
        for (int ii = 0; ii < 8; ii++) xv[ii] = sX[(ng + 16 * ii) * XSTRIDE + kg];
#pragma unroll
        for (int kk = 0; kk < 4; kk++) {
            float4 wv = sW[(4 * kg + kk) * 16 + fg];
#pragma unroll
            for (int ii = 0; ii < 8; ii++) {
                float xs = (kk == 0) ? xv[ii].x : (kk == 1) ? xv[ii].y
                         : (kk == 2) ? xv[ii].z : xv[ii].w;
                acc[ii].x += wv.x * xs;
                acc[ii].y += wv.y * xs;
                acc[ii].z += wv.z * xs;
                acc[ii].w += wv.w * xs;
            }
        }
    }

    ushort4* H4 = (ushort4*)Hn;
#pragma unroll
    for (int ii = 0; ii < 8; ii++) {
        int node = base + ng + 16 * ii;
        if (node < n) {
            float d = dinv[node];
            float4 o = acc[ii];
            ushort4 u;
            u.x = f2bf(o.x * d); u.y = f2bf(o.y * d);
            u.z = f2bf(o.z * d); u.w = f2bf(o.w * d);
            H4[(size_t)node * 16 + fg] = u;
        }
    }
}

// ---------------- gather (layers 1,2): 8 nodes/wave, 4 edges/iter ----------------
// lane = ns*8+f: node = wave*8+ns, feature octet f (features 8f..8f+8).
__global__ __launch_bounds__(256) void gather_layer(const int* __restrict__ rbeg,
                                                    const int* __restrict__ rend,
                                                    const int* __restrict__ eidx,
                                                    const float* __restrict__ dinv,
                                                    const unsigned short* __restrict__ Hn,
                                                    const float* __restrict__ b,
                                                    unsigned short* __restrict__ OUT, int n) {
    int wv = (blockIdx.x * blockDim.x + threadIdx.x) >> 6;
    int lane = threadIdx.x & 63;
    int ns = lane >> 3, f = lane & 7;
    int node = wv * 8 + ns;
    bool valid = node < n;
    int beg = valid ? rbeg[node] : 0;
    int end = valid ? rend[node] : 0;
    const char* Hb = (const char*)Hn;

    float a0 = 0.f, a1 = 0.f, a2 = 0.f, a3 = 0.f;
    float a4 = 0.f, a5 = 0.f, a6 = 0.f, a7 = 0.f;
    int k = beg;
    for (; k + 3 < end; k += 4) {
        int o1 = eidx[k], o2 = eidx[k + 1], o3 = eidx[k + 2], o4 = eidx[k + 3];
        uint4 p = *(const uint4*)(Hb + o1 + f * 16);
        uint4 q = *(const uint4*)(Hb + o2 + f * 16);
        uint4 r = *(const uint4*)(Hb + o3 + f * 16);
        uint4 w = *(const uint4*)(Hb + o4 + f * 16);
        a0 += (bfl(p.x) + bfl(q.x)) + (bfl(r.x) + bfl(w.x));
        a1 += (bfh(p.x) + bfh(q.x)) + (bfh(r.x) + bfh(w.x));
        a2 += (bfl(p.y) + bfl(q.y)) + (bfl(r.y) + bfl(w.y));
        a3 += (bfh(p.y) + bfh(q.y)) + (bfh(r.y) + bfh(w.y));
        a4 += (bfl(p.z) + bfl(q.z)) + (bfl(r.z) + bfl(w.z));
        a5 += (bfh(p.z) + bfh(q.z)) + (bfh(r.z) + bfh(w.z));
        a6 += (bfl(p.w) + bfl(q.w)) + (bfl(r.w) + bfl(w.w));
        a7 += (bfh(p.w) + bfh(q.w)) + (bfh(r.w) + bfh(w.w));
    }
    for (; k < end; k++) {
        int o1 = eidx[k];
        uint4 p = *(const uint4*)(Hb + o1 + f * 16);
        a0 += bfl(p.x); a1 += bfh(p.x);
        a2 += bfl(p.y); a3 += bfh(p.y);
        a4 += bfl(p.z); a5 += bfh(p.z);
        a6 += bfl(p.w); a7 += bfh(p.w);
    }

    if (valid) {
        float di = dinv[node];
        uint4 hs = *(const uint4*)(Hb + (size_t)node * 128 + f * 16);
        float4 b0 = ((const float4*)b)[2 * f];
        float4 b1 = ((const float4*)b)[2 * f + 1];
        float v0 = fmaxf(di * (a0 + bfl(hs.x)) + b0.x, 0.f);
        float v1 = fmaxf(di * (a1 + bfh(hs.x)) + b0.y, 0.f);
        float v2 = fmaxf(di * (a2 + bfl(hs.y)) + b0.z, 0.f);
        float v3 = fmaxf(di * (a3 + bfh(hs.y)) + b0.w, 0.f);
        float v4 = fmaxf(di * (a4 + bfl(hs.z)) + b1.x, 0.f);
        float v5 = fmaxf(di * (a5 + bfh(hs.z)) + b1.y, 0.f);
        float v6 = fmaxf(di * (a6 + bfl(hs.w)) + b1.z, 0.f);
        float v7 = fmaxf(di * (a7 + bfh(hs.w)) + b1.w, 0.f);
        uint4 u;
        u.x = pack2bf(v0, v1); u.y = pack2bf(v2, v3);
        u.z = pack2bf(v4, v5); u.w = pack2bf(v6, v7);
        ((uint4*)OUT)[(size_t)node * 8 + f] = u;
    }
}

// ---------------- layer-3 gather fused with pooling dot: writes pdot[node] ----------------
__global__ __launch_bounds__(256) void gather_pool(const int* __restrict__ rbeg,
                                                   const int* __restrict__ rend,
                                                   const int* __restrict__ eidx,
                                                   const float* __restrict__ dinv,
                                                   const unsigned short* __restrict__ Hn,
                                                   const float* __restrict__ b,
                                                   const float* __restrict__ Wl,
                                                   float* __restrict__ pdot, int n) {
    int wv = (blockIdx.x * blockDim.x + threadIdx.x) >> 6;
    int lane = threadIdx.x & 63;
    int ns = lane >> 3, f = lane & 7;
    int node = wv * 8 + ns;
    bool valid = node < n;
    int beg = valid ? rbeg[node] : 0;
    int end = valid ? rend[node] : 0;
    const char* Hb = (const char*)Hn;

    float a0 = 0.f, a1 = 0.f, a2 = 0.f, a3 = 0.f;
    float a4 = 0.f, a5 = 0.f, a6 = 0.f, a7 = 0.f;
    int k = beg;
    for (; k + 3 < end; k += 4) {
        int o1 = eidx[k], o2 = eidx[k + 1], o3 = eidx[k + 2], o4 = eidx[k + 3];
        uint4 p = *(const uint4*)(Hb + o1 + f * 16);
        uint4 q = *(const uint4*)(Hb + o2 + f * 16);
        uint4 r = *(const uint4*)(Hb + o3 + f * 16);
        uint4 w = *(const uint4*)(Hb + o4 + f * 16);
        a0 += (bfl(p.x) + bfl(q.x)) + (bfl(r.x) + bfl(w.x));
        a1 += (bfh(p.x) + bfh(q.x)) + (bfh(r.x) + bfh(w.x));
        a2 += (bfl(p.y) + bfl(q.y)) + (bfl(r.y) + bfl(w.y));
        a3 += (bfh(p.y) + bfh(q.y)) + (bfh(r.y) + bfh(w.y));
        a4 += (bfl(p.z) + bfl(q.z)) + (bfl(r.z) + bfl(w.z));
        a5 += (bfh(p.z) + bfh(q.z)) + (bfh(r.z) + bfh(w.z));
        a6 += (bfl(p.w) + bfl(q.w)) + (bfl(r.w) + bfl(w.w));
        a7 += (bfh(p.w) + bfh(q.w)) + (bfh(r.w) + bfh(w.w));
    }
    for (; k < end; k++) {
        int o1 = eidx[k];
        uint4 p = *(const uint4*)(Hb + o1 + f * 16);
        a0 += bfl(p.x); a1 += bfh(p.x);
        a2 += bfl(p.y); a3 += bfh(p.y);
        a4 += bfl(p.z); a5 += bfh(p.z);
        a6 += bfl(p.w); a7 += bfh(p.w);
    }

    float di = valid ? dinv[node] : 0.f;
    uint4 hs = valid ? *(const uint4*)(Hb + (size_t)node * 128 + f * 16)
                     : make_uint4(0u, 0u, 0u, 0u);
    float4 b0 = ((const float4*)b)[2 * f];
    float4 b1 = ((const float4*)b)[2 * f + 1];
    float4 w0 = ((const float4*)Wl)[2 * f];
    float4 w1 = ((const float4*)Wl)[2 * f + 1];
    float d = 0.f;
    d += fmaxf(di * (a0 + bfl(hs.x)) + b0.x, 0.f) * w0.x;
    d += fmaxf(di * (a1 + bfh(hs.x)) + b0.y, 0.f) * w0.y;
    d += fmaxf(di * (a2 + bfl(hs.y)) + b0.z, 0.f) * w0.z;
    d += fmaxf(di * (a3 + bfh(hs.y)) + b0.w, 0.f) * w0.w;
    d += fmaxf(di * (a4 + bfl(hs.z)) + b1.x, 0.f) * w1.x;
    d += fmaxf(di * (a5 + bfh(hs.z)) + b1.y, 0.f) * w1.y;
    d += fmaxf(di * (a6 + bfl(hs.w)) + b1.z, 0.f) * w1.z;
    d += fmaxf(di * (a7 + bfh(hs.w)) + b1.w, 0.f) * w1.w;
    // reduce across the 8 feature lanes of this node group (masks 1,2,4)
#pragma unroll
    for (int m = 1; m <= 4; m <<= 1) d += __shfl_xor(d, m);
    if (valid && f == 0) pdot[node] = d;
}

// ---------------- final: per-graph mean of pdot + bias ----------------
__global__ __launch_bounds__(64) void final_out(const float* __restrict__ pdot,
                                                const int* __restrict__ batch,
                                                const float* __restrict__ bl,
                                                float* __restrict__ out) {
    int g = blockIdx.x;
    __shared__ int slo, shi;
    int lane = threadIdx.x;
    if (lane == 0) {
        int a = 0, b = N_NODES;
        while (a < b) { int m = (a + b) >> 1; if (batch[m] < g) a = m + 1; else b = m; }
        slo = a;
        b = N_NODES;
        while (a < b) { int m = (a + b) >> 1; if (batch[m] < g + 1) a = m + 1; else b = m; }
        shi = a;
    }
    __syncthreads();
    int lo = slo, hi = shi;
    float acc = 0.f;
    for (int i = lo + lane; i < hi; i += 64) acc += pdot[i];
#pragma unroll
    for (int off = 32; off > 0; off >>= 1) acc += __shfl_down(acc, off);
    if (lane == 0) {
        float cnt = (float)(hi - lo);
        out[g] = acc / fmaxf(cnt, 1.0f) + bl[0];
    }
}

extern "C" void kernel_launch(void* const* d_in, const int* in_sizes, int n_in,
                              void* d_out, int out_size, void* d_ws, size_t ws_size,
                              hipStream_t stream) {
    const float* x     = (const float*)d_in[0];
    const int*   src   = (const int*)d_in[1];
    const int*   dst   = (const int*)d_in[2];
    const int*   batch = (const int*)d_in[3];
    const float* W1 = (const float*)d_in[4];  const float* b1 = (const float*)d_in[5];
    const float* W2 = (const float*)d_in[6];  const float* b2 = (const float*)d_in[7];
    const float* W3 = (const float*)d_in[8];  const float* b3 = (const float*)d_in[9];
    const float* Wl = (const float*)d_in[10]; const float* bl = (const float*)d_in[11];
    float* out = (float*)d_out;

    char* ws = (char*)d_ws;
    unsigned short* Abf = (unsigned short*)ws;                       // N*F bf16 (Hn)
    unsigned short* Bbf = Abf + (size_t)N_NODES * F;                 // N*F bf16 (H)
    float* dinv    = (float*)(Bbf + (size_t)N_NODES * F);            // N
    float* pdot    = dinv + N_NODES;                                 // N
    int*   rbeg    = (int*)(pdot + N_NODES);                         // N
    int*   rend    = rbeg + N_NODES;                                 // N
    int*   bcur    = rend + N_NODES;                                 // NBUCK
    unsigned int* bpair = (unsigned int*)(bcur + NBUCK);             // NBUCK*CAP
    int*   eidx    = (int*)(bpair + (size_t)NBUCK * CAP);            // NBUCK*CAP

    const int GEMM_GRID   = (N_NODES + 127) / 128;                   // 391
    const int GATHER_GRID = (N_NODES + 31) / 32;                     // 1563 (8 nodes/wave)

    // ---- preprocessing: padded-CSR build (rbeg/rend, eidx, dinv) ----
    hipMemsetAsync(bcur, 0, NBUCK * sizeof(int), stream);
    partition_edges<<<P3_GRID, 256, 0, stream>>>(src, dst, bcur, bpair);
    bucket_sort<<<NBUCK, 256, 0, stream>>>(bpair, bcur, eidx, rbeg, rend, dinv);

    // ---- layer 1 (f32 input) ----
    gemm64_t<false><<<GEMM_GRID, 256, 0, stream>>>((const void*)x, W1, dinv, Abf, N_NODES);
    gather_layer<<<GATHER_GRID, 256, 0, stream>>>(rbeg, rend, eidx, dinv, Abf, b1, Bbf, N_NODES);

    // ---- layer 2 (bf16 input) ----
    gemm64_t<true><<<GEMM_GRID, 256, 0, stream>>>((const void*)Bbf, W2, dinv, Abf, N_NODES);
    gather_layer<<<GATHER_GRID, 256, 0, stream>>>(rbeg, rend, eidx, dinv, Abf, b2, Bbf, N_NODES);

    // ---- layer 3 (bf16 input), gather fused with pooling dot ----
    gemm64_t<true><<<GEMM_GRID, 256, 0, stream>>>((const void*)Bbf, W3, dinv, Abf, N_NODES);
    gather_pool<<<GATHER_GRID, 256, 0, stream>>>(rbeg, rend, eidx, dinv, Abf, b3, Wl, pdot, N_NODES);

    // ---- final: per-graph mean + bias ----
    final_out<<<N_GRAPHS, 64, 0, stream>>>(pdot, batch, bl, out);
}

// Round 15
// 208.198 us; speedup vs baseline: 1.1349x; 1.0120x over previous
//
#include <hip/hip_runtime.h>

#define N_NODES 50000
#define N_EDGES 800000
#define N_GRAPHS 256
#define F 64
#define NBUCK 196          // ceil(50000/256) coarse buckets (dst>>8)
#define CAP 5120           // per-bucket capacity incl. 4-align padding
#define P3_TILE 2048
#define P3_GRID ((N_EDGES + P3_TILE - 1) / P3_TILE)
#define BCAP 6144
#define ZOFF (N_NODES * 128) // byte offset of the zero row in Hn

// ---- bf16 helpers (RTN), all math stays f32 ----
__device__ __forceinline__ unsigned short f2bf(float f) {
    union { float f; unsigned u; } c; c.f = f;
    unsigned u = c.u + 0x7FFFu + ((c.u >> 16) & 1u);
    return (unsigned short)(u >> 16);
}
__device__ __forceinline__ unsigned pack2bf(float lo, float hi) {
    return (unsigned)f2bf(lo) | ((unsigned)f2bf(hi) << 16);
}
__device__ __forceinline__ float bfl(unsigned u) {
    union { unsigned u; float f; } c; c.u = u << 16; return c.f;
}
__device__ __forceinline__ float bfh(unsigned u) {
    union { unsigned u; float f; } c; c.u = u & 0xFFFF0000u; return c.f;
}

// ---------------- P1: partition edges into fixed-capacity buckets ----------------
__global__ __launch_bounds__(256) void partition_edges(const int* __restrict__ src,
                                                       const int* __restrict__ dst,
                                                       int* __restrict__ bcur,
                                                       unsigned int* __restrict__ bpair) {
    __shared__ int bh[NBUCK], bloc[NBUCK], bpos[NBUCK];
    int t = threadIdx.x;
    int lo = blockIdx.x * P3_TILE;
    int hi = min(lo + P3_TILE, N_EDGES);
    for (int i = t; i < NBUCK; i += 256) { bh[i] = 0; bpos[i] = 0; }
    __syncthreads();
    for (int e = lo + t; e < hi; e += 256) atomicAdd(&bh[dst[e] >> 8], 1);
    __syncthreads();
    for (int i = t; i < NBUCK; i += 256)
        bloc[i] = bh[i] ? atomicAdd(&bcur[i], bh[i]) : 0;
    __syncthreads();
    for (int e = lo + t; e < hi; e += 256) {
        int d = dst[e];
        int b = d >> 8;
        int r = atomicAdd(&bpos[b], 1);
        bpair[(size_t)b * CAP + bloc[b] + r] = ((unsigned)src[e] << 8) | (unsigned)(d & 255);
    }
}

// ---------------- P2: per-bucket counting sort -> 4-aligned padded CSR ----------------
// eidx runs are padded to a multiple of 4 with ZOFF (zero-row) sentinels.
// Also zeroes the Hn zero row (row N of Abf).
__global__ __launch_bounds__(256) void bucket_sort(const unsigned int* __restrict__ bpair,
                                                   const int* __restrict__ bcur,
                                                   int* __restrict__ eidx,
                                                   int* __restrict__ rbeg,
                                                   int* __restrict__ rend,
                                                   float* __restrict__ dinv,
                                                   unsigned short* __restrict__ Abf) {
    __shared__ int cnt[256], s[256], pos[256];
    __shared__ int lout[BCAP];
    int b = blockIdx.x, t = threadIdx.x;
    int base = b * CAP;
    int sz = bcur[b];

    if (b == 0 && t < 8) ((uint4*)Abf)[(size_t)N_NODES * 8 + t] = make_uint4(0u, 0u, 0u, 0u);

    cnt[t] = 0;
    __syncthreads();
    for (int i = t; i < sz; i += 256) atomicAdd(&cnt[bpair[base + i] & 255], 1);
    __syncthreads();
    int v = cnt[t];
    int pv = (v + 3) & ~3;          // padded to multiple of 4
    s[t] = pv;
    __syncthreads();
    for (int off = 1; off < 256; off <<= 1) {
        int u = (t >= off) ? s[t - off] : 0;
        __syncthreads();
        s[t] += u;
        __syncthreads();
    }
    int excl = s[t] - pv;            // padded exclusive prefix
    pos[t] = excl;
    int node = b * 256 + t;
    if (node < N_NODES) {
        rbeg[node] = base + excl;
        rend[node] = base + excl + pv;                 // padded end (loop bound)
        dinv[node] = 1.0f / sqrtf((float)v + 1.0f);    // actual degree +1 self-loop
    }
    int padtot = s[255];             // total padded size of this bucket
    __syncthreads();

    // scatter actual edges
    for (int i = t; i < sz; i += 256) {
        unsigned p = bpair[base + i];
        int r = atomicAdd(&pos[p & 255], 1);
        lout[r] = (int)((p >> 8) << 7);   // src byte offset (src*128, bf16 row)
    }
    __syncthreads();
    // fill pad slots with zero-row sentinel (each thread pads its own node run)
    for (int j = v; j < pv; j++) lout[excl + j] = ZOFF;
    __syncthreads();
    for (int i = t; i < padtot; i += 256) eidx[base + i] = lout[i];
}

// ---------------- GEMM + dinv fold: Hn[i,:] = bf16( (X[i,:] @ W) * dinv[i] ) ----------------
#define XSTRIDE 17
template <bool BF16IN>
__global__ __launch_bounds__(256) void gemm64_t(const void* __restrict__ Xv,
                                                const float* __restrict__ W,
                                                const float* __restrict__ dinv,
                                                unsigned short* __restrict__ Hn, int n) {
    __shared__ float4 sW[64 * 16];
    __shared__ float4 sX[128 * XSTRIDE];
    int tid = threadIdx.x;
    int base = blockIdx.x * 128;

    const float4* W4 = (const float4*)W;
    for (int i = tid; i < 64 * 16; i += 256) sW[i] = W4[i];
    if (BF16IN) {
        const uint4* X4 = (const uint4*)Xv;    // row = 8 uint4 (64 bf16)
        for (int i = tid; i < 128 * 8; i += 256) {
            int r = i >> 3, c = i & 7;
            int node = base + r;
            uint4 u = (node < n) ? X4[(size_t)node * 8 + c]
                                 : make_uint4(0u, 0u, 0u, 0u);
            sX[r * XSTRIDE + 2 * c]     = make_float4(bfl(u.x), bfh(u.x), bfl(u.y), bfh(u.y));
            sX[r * XSTRIDE + 2 * c + 1] = make_float4(bfl(u.z), bfh(u.z), bfl(u.w), bfh(u.w));
        }
    } else {
        const float4* X4 = (const float4*)Xv;
        for (int i = tid; i < 128 * 16; i += 256) {
            int r = i >> 4, kg = i & 15;
            int node = base + r;
            sX[r * XSTRIDE + kg] = (node < n) ? X4[(size_t)node * 16 + kg]
                                              : make_float4(0.f, 0.f, 0.f, 0.f);
        }
    }
    __syncthreads();

    int fg = tid & 15;
    int ng = tid >> 4;
    float4 acc[8];
#pragma unroll
    for (int ii = 0; ii < 8; ii++) acc[ii] = make_float4(0.f, 0.f, 0.f, 0.f);

    for (int kg = 0; kg < 16; kg++) {
        float4 xv[8];
#pragma unroll
        for (int ii = 0; ii < 8; ii++) xv[ii] = sX[(ng + 16 * ii) * XSTRIDE + kg];
#pragma unroll
        for (int kk = 0; kk < 4; kk++) {
            float4 wv = sW[(4 * kg + kk) * 16 + fg];
#pragma unroll
            for (int ii = 0; ii < 8; ii++) {
                float xs = (kk == 0) ? xv[ii].x : (kk == 1) ? xv[ii].y
                         : (kk == 2) ? xv[ii].z : xv[ii].w;
                acc[ii].x += wv.x * xs;
                acc[ii].y += wv.y * xs;
                acc[ii].z += wv.z * xs;
                acc[ii].w += wv.w * xs;
            }
        }
    }

    ushort4* H4 = (ushort4*)Hn;
#pragma unroll
    for (int ii = 0; ii < 8; ii++) {
        int node = base + ng + 16 * ii;
        if (node < n) {
            float d = dinv[node];
            float4 o = acc[ii];
            ushort4 u;
            u.x = f2bf(o.x * d); u.y = f2bf(o.y * d);
            u.z = f2bf(o.z * d); u.w = f2bf(o.w * d);
            H4[(size_t)node * 16 + fg] = u;
        }
    }
}

// ---------------- gather (layers 1,2): 8 nodes/wave, aligned int4 eidx, no tail ----------------
__global__ __launch_bounds__(256) void gather_layer(const int* __restrict__ rbeg,
                                                    const int* __restrict__ rend,
                                                    const int* __restrict__ eidx,
                                                    const float* __restrict__ dinv,
                                                    const unsigned short* __restrict__ Hn,
                                                    const float* __restrict__ b,
                                                    unsigned short* __restrict__ OUT, int n) {
    int wv = (blockIdx.x * blockDim.x + threadIdx.x) >> 6;
    int lane = threadIdx.x & 63;
    int ns = lane >> 3, f = lane & 7;
    int node = wv * 8 + ns;
    bool valid = node < n;
    int beg = valid ? rbeg[node] : 0;
    int end = valid ? rend[node] : 0;
    const char* Hb = (const char*)Hn;

    float a0 = 0.f, a1 = 0.f, a2 = 0.f, a3 = 0.f;
    float a4 = 0.f, a5 = 0.f, a6 = 0.f, a7 = 0.f;
    for (int k = beg; k < end; k += 4) {
        int4 o = *(const int4*)(eidx + k);
        uint4 p = *(const uint4*)(Hb + o.x + f * 16);
        uint4 q = *(const uint4*)(Hb + o.y + f * 16);
        uint4 r = *(const uint4*)(Hb + o.z + f * 16);
        uint4 w = *(const uint4*)(Hb + o.w + f * 16);
        a0 += (bfl(p.x) + bfl(q.x)) + (bfl(r.x) + bfl(w.x));
        a1 += (bfh(p.x) + bfh(q.x)) + (bfh(r.x) + bfh(w.x));
        a2 += (bfl(p.y) + bfl(q.y)) + (bfl(r.y) + bfl(w.y));
        a3 += (bfh(p.y) + bfh(q.y)) + (bfh(r.y) + bfh(w.y));
        a4 += (bfl(p.z) + bfl(q.z)) + (bfl(r.z) + bfl(w.z));
        a5 += (bfh(p.z) + bfh(q.z)) + (bfh(r.z) + bfh(w.z));
        a6 += (bfl(p.w) + bfl(q.w)) + (bfl(r.w) + bfl(w.w));
        a7 += (bfh(p.w) + bfh(q.w)) + (bfh(r.w) + bfh(w.w));
    }

    if (valid) {
        float di = dinv[node];
        uint4 hs = *(const uint4*)(Hb + (size_t)node * 128 + f * 16);
        float4 b0 = ((const float4*)b)[2 * f];
        float4 b1 = ((const float4*)b)[2 * f + 1];
        float v0 = fmaxf(di * (a0 + bfl(hs.x)) + b0.x, 0.f);
        float v1 = fmaxf(di * (a1 + bfh(hs.x)) + b0.y, 0.f);
        float v2 = fmaxf(di * (a2 + bfl(hs.y)) + b0.z, 0.f);
        float v3 = fmaxf(di * (a3 + bfh(hs.y)) + b0.w, 0.f);
        float v4 = fmaxf(di * (a4 + bfl(hs.z)) + b1.x, 0.f);
        float v5 = fmaxf(di * (a5 + bfh(hs.z)) + b1.y, 0.f);
        float v6 = fmaxf(di * (a6 + bfl(hs.w)) + b1.z, 0.f);
        float v7 = fmaxf(di * (a7 + bfh(hs.w)) + b1.w, 0.f);
        uint4 u;
        u.x = pack2bf(v0, v1); u.y = pack2bf(v2, v3);
        u.z = pack2bf(v4, v5); u.w = pack2bf(v6, v7);
        ((uint4*)OUT)[(size_t)node * 8 + f] = u;
    }
}

// ---------------- layer-3 gather fused with pooling dot: writes pdot[node] ----------------
__global__ __launch_bounds__(256) void gather_pool(const int* __restrict__ rbeg,
                                                   const int* __restrict__ rend,
                                                   const int* __restrict__ eidx,
                                                   const float* __restrict__ dinv,
                                                   const unsigned short* __restrict__ Hn,
                                                   const float* __restrict__ b,
                                                   const float* __restrict__ Wl,
                                                   float* __restrict__ pdot, int n) {
    int wv = (blockIdx.x * blockDim.x + threadIdx.x) >> 6;
    int lane = threadIdx.x & 63;
    int ns = lane >> 3, f = lane & 7;
    int node = wv * 8 + ns;
    bool valid = node < n;
    int beg = valid ? rbeg[node] : 0;
    int end = valid ? rend[node] : 0;
    const char* Hb = (const char*)Hn;

    float a0 = 0.f, a1 = 0.f, a2 = 0.f, a3 = 0.f;
    float a4 = 0.f, a5 = 0.f, a6 = 0.f, a7 = 0.f;
    for (int k = beg; k < end; k += 4) {
        int4 o = *(const int4*)(eidx + k);
        uint4 p = *(const uint4*)(Hb + o.x + f * 16);
        uint4 q = *(const uint4*)(Hb + o.y + f * 16);
        uint4 r = *(const uint4*)(Hb + o.z + f * 16);
        uint4 w = *(const uint4*)(Hb + o.w + f * 16);
        a0 += (bfl(p.x) + bfl(q.x)) + (bfl(r.x) + bfl(w.x));
        a1 += (bfh(p.x) + bfh(q.x)) + (bfh(r.x) + bfh(w.x));
        a2 += (bfl(p.y) + bfl(q.y)) + (bfl(r.y) + bfl(w.y));
        a3 += (bfh(p.y) + bfh(q.y)) + (bfh(r.y) + bfh(w.y));
        a4 += (bfl(p.z) + bfl(q.z)) + (bfl(r.z) + bfl(w.z));
        a5 += (bfh(p.z) + bfh(q.z)) + (bfh(r.z) + bfh(w.z));
        a6 += (bfl(p.w) + bfl(q.w)) + (bfl(r.w) + bfl(w.w));
        a7 += (bfh(p.w) + bfh(q.w)) + (bfh(r.w) + bfh(w.w));
    }

    float di = valid ? dinv[node] : 0.f;
    uint4 hs = valid ? *(const uint4*)(Hb + (size_t)node * 128 + f * 16)
                     : make_uint4(0u, 0u, 0u, 0u);
    float4 b0 = ((const float4*)b)[2 * f];
    float4 b1 = ((const float4*)b)[2 * f + 1];
    float4 w0 = ((const float4*)Wl)[2 * f];
    float4 w1 = ((const float4*)Wl)[2 * f + 1];
    float d = 0.f;
    d += fmaxf(di * (a0 + bfl(hs.x)) + b0.x, 0.f) * w0.x;
    d += fmaxf(di * (a1 + bfh(hs.x)) + b0.y, 0.f) * w0.y;
    d += fmaxf(di * (a2 + bfl(hs.y)) + b0.z, 0.f) * w0.z;
    d += fmaxf(di * (a3 + bfh(hs.y)) + b0.w, 0.f) * w0.w;
    d += fmaxf(di * (a4 + bfl(hs.z)) + b1.x, 0.f) * w1.x;
    d += fmaxf(di * (a5 + bfh(hs.z)) + b1.y, 0.f) * w1.y;
    d += fmaxf(di * (a6 + bfl(hs.w)) + b1.z, 0.f) * w1.z;
    d += fmaxf(di * (a7 + bfh(hs.w)) + b1.w, 0.f) * w1.w;
#pragma unroll
    for (int m = 1; m <= 4; m <<= 1) d += __shfl_xor(d, m);
    if (valid && f == 0) pdot[node] = d;
}

// ---------------- final: per-graph mean of pdot + bias ----------------
__global__ __launch_bounds__(64) void final_out(const float* __restrict__ pdot,
                                                const int* __restrict__ batch,
                                                const float* __restrict__ bl,
                                                float* __restrict__ out) {
    int g = blockIdx.x;
    __shared__ int slo, shi;
    int lane = threadIdx.x;
    if (lane == 0) {
        int a = 0, b = N_NODES;
        while (a < b) { int m = (a + b) >> 1; if (batch[m] < g) a = m + 1; else b = m; }
        slo = a;
        b = N_NODES;
        while (a < b) { int m = (a + b) >> 1; if (batch[m] < g + 1) a = m + 1; else b = m; }
        shi = a;
    }
    __syncthreads();
    int lo = slo, hi = shi;
    float acc = 0.f;
    for (int i = lo + lane; i < hi; i += 64) acc += pdot[i];
#pragma unroll
    for (int off = 32; off > 0; off >>= 1) acc += __shfl_down(acc, off);
    if (lane == 0) {
        float cnt = (float)(hi - lo);
        out[g] = acc / fmaxf(cnt, 1.0f) + bl[0];
    }
}

extern "C" void kernel_launch(void* const* d_in, const int* in_sizes, int n_in,
                              void* d_out, int out_size, void* d_ws, size_t ws_size,
                              hipStream_t stream) {
    const float* x     = (const float*)d_in[0];
    const int*   src   = (const int*)d_in[1];
    const int*   dst   = (const int*)d_in[2];
    const int*   batch = (const int*)d_in[3];
    const float* W1 = (const float*)d_in[4];  const float* b1 = (const float*)d_in[5];
    const float* W2 = (const float*)d_in[6];  const float* b2 = (const float*)d_in[7];
    const float* W3 = (const float*)d_in[8];  const float* b3 = (const float*)d_in[9];
    const float* Wl = (const float*)d_in[10]; const float* bl = (const float*)d_in[11];
    float* out = (float*)d_out;

    char* ws = (char*)d_ws;
    unsigned short* Abf = (unsigned short*)ws;                       // (N+1)*F bf16 (Hn + zero row)
    unsigned short* Bbf = Abf + (size_t)(N_NODES + 1) * F;           // N*F bf16 (H)
    float* dinv    = (float*)(Bbf + (size_t)N_NODES * F);            // N
    float* pdot    = dinv + N_NODES;                                 // N
    int*   rbeg    = (int*)(pdot + N_NODES);                         // N
    int*   rend    = rbeg + N_NODES;                                 // N
    int*   bcur    = rend + N_NODES;                                 // NBUCK
    unsigned int* bpair = (unsigned int*)(bcur + NBUCK);             // NBUCK*CAP
    int*   eidx    = (int*)(bpair + (size_t)NBUCK * CAP);            // NBUCK*CAP

    const int GEMM_GRID   = (N_NODES + 127) / 128;                   // 391
    const int GATHER_GRID = (N_NODES + 31) / 32;                     // 1563 (8 nodes/wave)

    // ---- preprocessing: padded-CSR build (rbeg/rend, eidx, dinv, zero row) ----
    hipMemsetAsync(bcur, 0, NBUCK * sizeof(int), stream);
    partition_edges<<<P3_GRID, 256, 0, stream>>>(src, dst, bcur, bpair);
    bucket_sort<<<NBUCK, 256, 0, stream>>>(bpair, bcur, eidx, rbeg, rend, dinv, Abf);

    // ---- layer 1 (f32 input) ----
    gemm64_t<false><<<GEMM_GRID, 256, 0, stream>>>((const void*)x, W1, dinv, Abf, N_NODES);
    gather_layer<<<GATHER_GRID, 256, 0, stream>>>(rbeg, rend, eidx, dinv, Abf, b1, Bbf, N_NODES);

    // ---- layer 2 (bf16 input) ----
    gemm64_t<true><<<GEMM_GRID, 256, 0, stream>>>((const void*)Bbf, W2, dinv, Abf, N_NODES);
    gather_layer<<<GATHER_GRID, 256, 0, stream>>>(rbeg, rend, eidx, dinv, Abf, b2, Bbf, N_NODES);

    // ---- layer 3 (bf16 input), gather fused with pooling dot ----
    gemm64_t<true><<<GEMM_GRID, 256, 0, stream>>>((const void*)Bbf, W3, dinv, Abf, N_NODES);
    gather_pool<<<GATHER_GRID, 256, 0, stream>>>(rbeg, rend, eidx, dinv, Abf, b3, Wl, pdot, N_NODES);

    // ---- final: per-graph mean + bias ----
    final_out<<<N_GRAPHS, 64, 0, stream>>>(pdot, batch, bl, out);
}